// Round 1
// baseline (392.741 us; speedup 1.0000x reference)
//
#include <hip/hip_runtime.h>
#include <math.h>

#define N_NODES 50000
#define DEG 16
#define EPSF 1e-5f

__device__ __forceinline__ float wave_reduce_sum(float v) {
    #pragma unroll
    for (int off = 32; off >= 1; off >>= 1)
        v += __shfl_xor(v, off, 64);
    return v;
}

// ---------------------------------------------------------------------------
// K1: feat = [emb0[x0] | emb1[x1] | emb2[x2]]  (256)
//     t = feat @ W_in + b_in   (256x256)
//     l1 = log0(exp0(t))           -> ws
// Block: 256 threads, 32 nodes per block.
// ---------------------------------------------------------------------------
__global__ __launch_bounds__(256) void k_encode_fc(
    const int* __restrict__ x,
    const float* __restrict__ emb0, const float* __restrict__ emb1,
    const float* __restrict__ emb2,
    const float* __restrict__ W, const float* __restrict__ b,
    float* __restrict__ l1)
{
    __shared__ float feat[32][264];   // 32 nodes x 256 (stride 264 for 16B-aligned b128)
    const int t  = threadIdx.x;
    const int n0 = blockIdx.x * 32;

    // ---- stage: thread t -> node nl = t>>3, segment seg = t&7 (32 floats) ----
    {
        const int nl  = t >> 3;
        const int seg = t & 7;
        const int node = n0 + nl;
        const int k0 = seg * 32;
        const float* p;
        if (node < N_NODES) {
            if (seg < 3)      p = emb0 + (size_t)x[node * 3 + 0] * 96 + k0;
            else if (seg < 6) p = emb1 + (size_t)x[node * 3 + 1] * 96 + (k0 - 96);
            else              p = emb2 + (size_t)x[node * 3 + 2] * 64 + (k0 - 192);
        } else {
            p = emb0;   // safe dummy row
        }
        #pragma unroll
        for (int i = 0; i < 8; i++) {
            float4 v = *(const float4*)(p + 4 * i);
            *(float4*)&feat[nl][k0 + 4 * i] = v;
        }
    }
    __syncthreads();

    // ---- GEMM: thread computes 8 nodes x 4 cols ----
    const int cg = t & 63;   // col group: cols cg*4 .. cg*4+3
    const int ng = t >> 6;   // node group: local nodes ng*8 .. ng*8+7 (== wave id)
    float acc[8][4];
    #pragma unroll
    for (int n = 0; n < 8; n++) {
        acc[n][0] = 0.f; acc[n][1] = 0.f; acc[n][2] = 0.f; acc[n][3] = 0.f;
    }

    for (int k = 0; k < 256; k += 4) {
        float wreg[4][4];
        #pragma unroll
        for (int kk = 0; kk < 4; kk++) {
            float4 wv = *(const float4*)&W[(size_t)(k + kk) * 256 + cg * 4];
            wreg[kk][0] = wv.x; wreg[kk][1] = wv.y; wreg[kk][2] = wv.z; wreg[kk][3] = wv.w;
        }
        #pragma unroll
        for (int n = 0; n < 8; n++) {
            float4 f = *(const float4*)&feat[ng * 8 + n][k];
            float fk[4] = { f.x, f.y, f.z, f.w };
            #pragma unroll
            for (int kk = 0; kk < 4; kk++) {
                #pragma unroll
                for (int c = 0; c < 4; c++)
                    acc[n][c] = fmaf(fk[kk], wreg[kk][c], acc[n][c]);
            }
        }
    }

    // ---- epilogue: +bias, l1 = log0(exp0(t)) ----
    const float4 bv = *(const float4*)&b[cg * 4];
    #pragma unroll
    for (int n = 0; n < 8; n++) {
        float a0 = acc[n][0] + bv.x, a1 = acc[n][1] + bv.y;
        float a2 = acc[n][2] + bv.z, a3 = acc[n][3] + bv.w;
        float d = wave_reduce_sum(a0 * a0 + a1 * a1 + a2 * a2 + a3 * a3);
        float norm = sqrtf(d);
        float nm = fmaxf(norm, EPSF);
        float se = tanhf(nm) / nm;          // exp0 scale
        float nh = se * norm;               // ||exp0(t)||
        float nc = fminf(fmaxf(nh, EPSF), 1.f - EPSF);
        float s  = se * (atanhf(nc) / nc);  // combined exp0+log0 scale
        const int node = n0 + ng * 8 + n;
        if (node < N_NODES) {
            float4 o; o.x = s * a0; o.y = s * a1; o.z = s * a2; o.w = s * a3;
            *(float4*)&l1[(size_t)node * 256 + cg * 4] = o;
        }
    }
}

// ---------------------------------------------------------------------------
// K2: hat layer: z = (l_in[v] + sum_j l_in[src[16v+j]]) / 17
//     h = exp0(z); if relu: h = relu(h); l_out = log0(h)
// Wave per node, 4 waves per block.
// ---------------------------------------------------------------------------
__global__ __launch_bounds__(256) void k_hat(
    const float* __restrict__ lin, const int* __restrict__ src,
    float* __restrict__ lout, int do_relu)
{
    const int lane = threadIdx.x & 63;
    const int v = blockIdx.x * 4 + (threadIdx.x >> 6);
    if (v >= N_NODES) return;

    int sl_ = src[(size_t)v * DEG + (lane & 15)];
    float4 acc = *(const float4*)&lin[(size_t)v * 256 + lane * 4];
    #pragma unroll
    for (int j = 0; j < DEG; j++) {
        int s = __shfl(sl_, j, 64);
        float4 m = *(const float4*)&lin[(size_t)s * 256 + lane * 4];
        acc.x += m.x; acc.y += m.y; acc.z += m.z; acc.w += m.w;
    }
    const float inv = 1.f / (float)(DEG + 1);
    float zx = acc.x * inv, zy = acc.y * inv, zz = acc.z * inv, zw = acc.w * inv;

    float d = wave_reduce_sum(zx * zx + zy * zy + zz * zz + zw * zw);
    float norm = sqrtf(d);
    float nm = fmaxf(norm, EPSF);
    float se = tanhf(nm) / nm;
    float hx = se * zx, hy = se * zy, hz = se * zz, hw = se * zw;

    float nh;
    if (do_relu) {
        hx = fmaxf(hx, 0.f); hy = fmaxf(hy, 0.f);
        hz = fmaxf(hz, 0.f); hw = fmaxf(hw, 0.f);
        nh = sqrtf(wave_reduce_sum(hx * hx + hy * hy + hz * hz + hw * hw));
    } else {
        nh = se * norm;
    }
    float nc = fminf(fmaxf(nh, EPSF), 1.f - EPSF);
    float s2 = atanhf(nc) / nc;

    float4 o; o.x = s2 * hx; o.y = s2 * hy; o.z = s2 * hz; o.w = s2 * hw;
    *(float4*)&lout[(size_t)v * 256 + lane * 4] = o;
}

// ---------------------------------------------------------------------------
// K3: hat layer (no relu) producing l3 rows in LDS, then
//     out = exp0(l3 @ W_out + b_out)   (256x128)
// Block: 256 threads, 32 nodes; wave w gathers 8 nodes sequentially.
// ---------------------------------------------------------------------------
__global__ __launch_bounds__(256) void k_hat_fc(
    const float* __restrict__ lin, const int* __restrict__ src,
    const float* __restrict__ W, const float* __restrict__ b,
    float* __restrict__ out)
{
    __shared__ float l3s[32][264];
    const int t = threadIdx.x;
    const int lane = t & 63;
    const int w = t >> 6;
    const int n0 = blockIdx.x * 32;

    // ---- phase A: gather-mean + exp0/log0 -> LDS ----
    for (int i = 0; i < 8; i++) {
        const int v = n0 + w * 8 + i;
        float ox = 0.f, oy = 0.f, oz = 0.f, ow = 0.f;
        if (v < N_NODES) {
            int sl_ = src[(size_t)v * DEG + (lane & 15)];
            float4 acc = *(const float4*)&lin[(size_t)v * 256 + lane * 4];
            #pragma unroll
            for (int j = 0; j < DEG; j++) {
                int s = __shfl(sl_, j, 64);
                float4 m = *(const float4*)&lin[(size_t)s * 256 + lane * 4];
                acc.x += m.x; acc.y += m.y; acc.z += m.z; acc.w += m.w;
            }
            const float inv = 1.f / (float)(DEG + 1);
            float zx = acc.x * inv, zy = acc.y * inv, zz = acc.z * inv, zw = acc.w * inv;
            float d = wave_reduce_sum(zx * zx + zy * zy + zz * zz + zw * zw);
            float norm = sqrtf(d);
            float nm = fmaxf(norm, EPSF);
            float se = tanhf(nm) / nm;
            float nh = se * norm;
            float nc = fminf(fmaxf(nh, EPSF), 1.f - EPSF);
            float s2 = se * (atanhf(nc) / nc);
            ox = s2 * zx; oy = s2 * zy; oz = s2 * zz; ow = s2 * zw;
        }
        float4 o; o.x = ox; o.y = oy; o.z = oz; o.w = ow;
        *(float4*)&l3s[w * 8 + i][lane * 4] = o;
    }
    __syncthreads();

    // ---- phase B: GEMM 32x256 * 256x128 + exp0 epilogue ----
    const int cg = lane;   // cols cg*2 .. cg*2+1
    const int ng = w;      // local nodes ng*8 .. ng*8+7
    float acc2[8][2];
    #pragma unroll
    for (int n = 0; n < 8; n++) { acc2[n][0] = 0.f; acc2[n][1] = 0.f; }

    for (int k = 0; k < 256; k += 4) {
        float wreg[4][2];
        #pragma unroll
        for (int kk = 0; kk < 4; kk++) {
            float2 wv = *(const float2*)&W[(size_t)(k + kk) * 128 + cg * 2];
            wreg[kk][0] = wv.x; wreg[kk][1] = wv.y;
        }
        #pragma unroll
        for (int n = 0; n < 8; n++) {
            float4 f = *(const float4*)&l3s[ng * 8 + n][k];
            float fk[4] = { f.x, f.y, f.z, f.w };
            #pragma unroll
            for (int kk = 0; kk < 4; kk++) {
                acc2[n][0] = fmaf(fk[kk], wreg[kk][0], acc2[n][0]);
                acc2[n][1] = fmaf(fk[kk], wreg[kk][1], acc2[n][1]);
            }
        }
    }

    const float2 bv = *(const float2*)&b[cg * 2];
    #pragma unroll
    for (int n = 0; n < 8; n++) {
        float a0 = acc2[n][0] + bv.x, a1 = acc2[n][1] + bv.y;
        float d = wave_reduce_sum(a0 * a0 + a1 * a1);
        float norm = sqrtf(d);
        float nm = fmaxf(norm, EPSF);
        float se = tanhf(nm) / nm;
        const int node = n0 + ng * 8 + n;
        if (node < N_NODES) {
            float2 o; o.x = se * a0; o.y = se * a1;
            *(float2*)&out[(size_t)node * 128 + cg * 2] = o;
        }
    }
}

extern "C" void kernel_launch(void* const* d_in, const int* in_sizes, int n_in,
                              void* d_out, int out_size, void* d_ws, size_t ws_size,
                              hipStream_t stream) {
    const int*   x     = (const int*)  d_in[0];
    const float* emb0  = (const float*)d_in[1];
    const float* emb1  = (const float*)d_in[2];
    const float* emb2  = (const float*)d_in[3];
    const float* W_in  = (const float*)d_in[4];
    const float* b_in  = (const float*)d_in[5];
    const float* W_out = (const float*)d_in[6];
    const float* b_out = (const float*)d_in[7];
    const int*   src0  = (const int*)  d_in[8];
    const int*   src1  = (const int*)  d_in[10];
    float* out = (float*)d_out;

    float* l1 = (float*)d_ws;                        // 50000*256 f32
    float* l2 = l1 + (size_t)N_NODES * 256;          // 50000*256 f32

    const int tiles = (N_NODES + 31) / 32;           // 1563

    k_encode_fc<<<tiles, 256, 0, stream>>>(x, emb0, emb1, emb2, W_in, b_in, l1);
    k_hat<<<(N_NODES + 3) / 4, 256, 0, stream>>>(l1, src0, l2, 1);
    k_hat_fc<<<tiles, 256, 0, stream>>>(l2, src1, W_out, b_out, out);
}

// Round 2
// 288.167 us; speedup vs baseline: 1.3629x; 1.3629x over previous
//
#include <hip/hip_runtime.h>
#include <math.h>

#define N_NODES 50000
#define DEG 16
#define EPSF 1e-5f

typedef unsigned int uint;
typedef unsigned short ushort;

__device__ __forceinline__ float wave_reduce_sum(float v) {
    #pragma unroll
    for (int off = 32; off >= 1; off >>= 1)
        v += __shfl_xor(v, off, 64);
    return v;
}

// reduce across each 32-lane group (halves hold duplicated data)
__device__ __forceinline__ float reduce32(float v) {
    #pragma unroll
    for (int off = 16; off >= 1; off >>= 1)
        v += __shfl_xor(v, off, 64);
    return v;
}

__device__ __forceinline__ float bf2f_lo(uint u) { return __uint_as_float(u << 16); }
__device__ __forceinline__ float bf2f_hi(uint u) { return __uint_as_float(u & 0xFFFF0000u); }
__device__ __forceinline__ uint  f2bf_rn(float f) {
    uint u = __float_as_uint(f);
    return (u + 0x7FFFu + ((u >> 16) & 1u)) >> 16;
}
__device__ __forceinline__ uint pack2(float a, float b) {
    return f2bf_rn(a) | (f2bf_rn(b) << 16);
}

// ---------------------------------------------------------------------------
// K1: feat = [emb0[x0] | emb1[x1] | emb2[x2]]  (256)
//     l1 = feat @ W_in + b_in        (log0(exp0(t)) == t identity)  -> bf16
// Block: 256 threads, 32 nodes.
// ---------------------------------------------------------------------------
__global__ __launch_bounds__(256) void k_encode_fc(
    const int* __restrict__ x,
    const float* __restrict__ emb0, const float* __restrict__ emb1,
    const float* __restrict__ emb2,
    const float* __restrict__ W, const float* __restrict__ b,
    ushort* __restrict__ l1)
{
    __shared__ float feat[32][264];
    const int t  = threadIdx.x;
    const int n0 = blockIdx.x * 32;

    {
        const int nl  = t >> 3;
        const int seg = t & 7;
        const int node = n0 + nl;
        const int k0 = seg * 32;
        const float* p;
        if (node < N_NODES) {
            if (seg < 3)      p = emb0 + (size_t)x[node * 3 + 0] * 96 + k0;
            else if (seg < 6) p = emb1 + (size_t)x[node * 3 + 1] * 96 + (k0 - 96);
            else              p = emb2 + (size_t)x[node * 3 + 2] * 64 + (k0 - 192);
        } else {
            p = emb0;
        }
        #pragma unroll
        for (int i = 0; i < 8; i++) {
            float4 v = *(const float4*)(p + 4 * i);
            *(float4*)&feat[nl][k0 + 4 * i] = v;
        }
    }
    __syncthreads();

    const int cg = t & 63;
    const int ng = t >> 6;
    float acc[8][4];
    #pragma unroll
    for (int n = 0; n < 8; n++) {
        acc[n][0] = 0.f; acc[n][1] = 0.f; acc[n][2] = 0.f; acc[n][3] = 0.f;
    }

    for (int k = 0; k < 256; k += 4) {
        float wreg[4][4];
        #pragma unroll
        for (int kk = 0; kk < 4; kk++) {
            float4 wv = *(const float4*)&W[(size_t)(k + kk) * 256 + cg * 4];
            wreg[kk][0] = wv.x; wreg[kk][1] = wv.y; wreg[kk][2] = wv.z; wreg[kk][3] = wv.w;
        }
        #pragma unroll
        for (int n = 0; n < 8; n++) {
            float4 f = *(const float4*)&feat[ng * 8 + n][k];
            float fk[4] = { f.x, f.y, f.z, f.w };
            #pragma unroll
            for (int kk = 0; kk < 4; kk++) {
                #pragma unroll
                for (int c = 0; c < 4; c++)
                    acc[n][c] = fmaf(fk[kk], wreg[kk][c], acc[n][c]);
            }
        }
    }

    const float4 bv = *(const float4*)&b[cg * 4];
    #pragma unroll
    for (int n = 0; n < 8; n++) {
        const int node = n0 + ng * 8 + n;
        if (node < N_NODES) {
            uint2 o;
            o.x = pack2(acc[n][0] + bv.x, acc[n][1] + bv.y);
            o.y = pack2(acc[n][2] + bv.z, acc[n][3] + bv.w);
            *(uint2*)&l1[(size_t)node * 256 + cg * 4] = o;
        }
    }
}

// ---------------------------------------------------------------------------
// K2: z = mean_17(l1 rows); h = relu(exp0(z)); l2 = log0(h)   (bf16 -> bf16)
// Wave per node; two 32-lane halves each gather 8 src rows (16 B/lane).
// ---------------------------------------------------------------------------
__global__ __launch_bounds__(256) void k_hat1(
    const ushort* __restrict__ lin, const int* __restrict__ src,
    ushort* __restrict__ lout)
{
    const int lane = threadIdx.x & 63;
    const int half = lane >> 5;
    const int li   = lane & 31;
    const int v    = blockIdx.x * 4 + (threadIdx.x >> 6);   // grid exact: 12500*4
    const int vv   = __builtin_amdgcn_readfirstlane(v);

    const int* sp = src + (size_t)vv * DEG;
    const size_t cb = (size_t)li << 4;   // 16B per lane within 512B row

    uint4 r[8];
    #pragma unroll
    for (int j = 0; j < 8; j++) {
        int s0 = sp[j];          // scalar loads (uniform addr)
        int s1 = sp[j + 8];
        size_t sidx = (size_t)(half ? s1 : s0);
        r[j] = *(const uint4*)((const char*)lin + (sidx << 9) + cb);
    }

    float acc[8];
    #pragma unroll
    for (int i = 0; i < 8; i++) acc[i] = 0.f;
    #pragma unroll
    for (int j = 0; j < 8; j++) {
        acc[0] += bf2f_lo(r[j].x); acc[1] += bf2f_hi(r[j].x);
        acc[2] += bf2f_lo(r[j].y); acc[3] += bf2f_hi(r[j].y);
        acc[4] += bf2f_lo(r[j].z); acc[5] += bf2f_hi(r[j].z);
        acc[6] += bf2f_lo(r[j].w); acc[7] += bf2f_hi(r[j].w);
    }
    if (half == 0) {   // self row once
        uint4 rs = *(const uint4*)((const char*)lin + ((size_t)vv << 9) + cb);
        acc[0] += bf2f_lo(rs.x); acc[1] += bf2f_hi(rs.x);
        acc[2] += bf2f_lo(rs.y); acc[3] += bf2f_hi(rs.y);
        acc[4] += bf2f_lo(rs.z); acc[5] += bf2f_hi(rs.z);
        acc[6] += bf2f_lo(rs.w); acc[7] += bf2f_hi(rs.w);
    }
    #pragma unroll
    for (int i = 0; i < 8; i++)
        acc[i] += __shfl_xor(acc[i], 32, 64);

    const float inv = 1.f / (float)(DEG + 1);
    float z[8], ss = 0.f;
    #pragma unroll
    for (int i = 0; i < 8; i++) { z[i] = acc[i] * inv; ss += z[i] * z[i]; }
    float d = reduce32(ss);
    float norm = sqrtf(d);
    float nm = fmaxf(norm, EPSF);
    float se = tanhf(nm) / nm;

    float h[8], s2s = 0.f;
    #pragma unroll
    for (int i = 0; i < 8; i++) { h[i] = fmaxf(se * z[i], 0.f); s2s += h[i] * h[i]; }
    float nh = sqrtf(reduce32(s2s));
    float nc = fminf(fmaxf(nh, EPSF), 1.f - EPSF);
    float s2 = atanhf(nc) / nc;

    uint p0 = pack2(s2 * h[0], s2 * h[1]);
    uint p1 = pack2(s2 * h[2], s2 * h[3]);
    uint p2 = pack2(s2 * h[4], s2 * h[5]);
    uint p3 = pack2(s2 * h[6], s2 * h[7]);
    uint2 u = half ? make_uint2(p2, p3) : make_uint2(p0, p1);
    *(uint2*)((char*)lout + ((size_t)vv << 9) + (li << 4) + (half << 3)) = u;
}

// ---------------------------------------------------------------------------
// K3: z2 = mean_17(l2 rows)   (bf16 -> f32; log0(exp0(z2)) == z2 identity)
// ---------------------------------------------------------------------------
__global__ __launch_bounds__(256) void k_hat2(
    const ushort* __restrict__ lin, const int* __restrict__ src,
    float* __restrict__ z2)
{
    const int lane = threadIdx.x & 63;
    const int half = lane >> 5;
    const int li   = lane & 31;
    const int v    = blockIdx.x * 4 + (threadIdx.x >> 6);
    const int vv   = __builtin_amdgcn_readfirstlane(v);

    const int* sp = src + (size_t)vv * DEG;
    const size_t cb = (size_t)li << 4;

    uint4 r[8];
    #pragma unroll
    for (int j = 0; j < 8; j++) {
        int s0 = sp[j];
        int s1 = sp[j + 8];
        size_t sidx = (size_t)(half ? s1 : s0);
        r[j] = *(const uint4*)((const char*)lin + (sidx << 9) + cb);
    }

    float acc[8];
    #pragma unroll
    for (int i = 0; i < 8; i++) acc[i] = 0.f;
    #pragma unroll
    for (int j = 0; j < 8; j++) {
        acc[0] += bf2f_lo(r[j].x); acc[1] += bf2f_hi(r[j].x);
        acc[2] += bf2f_lo(r[j].y); acc[3] += bf2f_hi(r[j].y);
        acc[4] += bf2f_lo(r[j].z); acc[5] += bf2f_hi(r[j].z);
        acc[6] += bf2f_lo(r[j].w); acc[7] += bf2f_hi(r[j].w);
    }
    if (half == 0) {
        uint4 rs = *(const uint4*)((const char*)lin + ((size_t)vv << 9) + cb);
        acc[0] += bf2f_lo(rs.x); acc[1] += bf2f_hi(rs.x);
        acc[2] += bf2f_lo(rs.y); acc[3] += bf2f_hi(rs.y);
        acc[4] += bf2f_lo(rs.z); acc[5] += bf2f_hi(rs.z);
        acc[6] += bf2f_lo(rs.w); acc[7] += bf2f_hi(rs.w);
    }
    #pragma unroll
    for (int i = 0; i < 8; i++)
        acc[i] += __shfl_xor(acc[i], 32, 64);

    const float inv = 1.f / (float)(DEG + 1);
    float4 sv;
    if (half == 0) {
        sv = make_float4(acc[0] * inv, acc[1] * inv, acc[2] * inv, acc[3] * inv);
    } else {
        sv = make_float4(acc[4] * inv, acc[5] * inv, acc[6] * inv, acc[7] * inv);
    }
    float* row = z2 + (size_t)vv * 256 + li * 8 + half * 4;
    *(float4*)row = sv;
}

// ---------------------------------------------------------------------------
// K4: out = exp0(z2 @ W_out + b_out)    (256x128 GEMM, f32)
// Block: 256 threads, 32 nodes.
// ---------------------------------------------------------------------------
__global__ __launch_bounds__(256) void k_fc_out(
    const float* __restrict__ z2,
    const float* __restrict__ W, const float* __restrict__ b,
    float* __restrict__ out)
{
    __shared__ float l3s[32][264];
    const int t = threadIdx.x;
    const int lane = t & 63;
    const int w = t >> 6;
    const int n0 = blockIdx.x * 32;

    // stage 32 rows (32 KB) coalesced
    #pragma unroll
    for (int i = 0; i < 8; i++) {
        const int nl = i * 4 + w;          // local node
        const int k  = lane * 4;
        const int node = n0 + nl;
        float4 v;
        if (node < N_NODES) v = *(const float4*)&z2[(size_t)node * 256 + k];
        else                v = make_float4(0.f, 0.f, 0.f, 0.f);
        *(float4*)&l3s[nl][k] = v;
    }
    __syncthreads();

    const int cg = lane;   // cols cg*2, cg*2+1
    const int ng = w;      // nodes ng*8 .. ng*8+7
    float acc2[8][2];
    #pragma unroll
    for (int n = 0; n < 8; n++) { acc2[n][0] = 0.f; acc2[n][1] = 0.f; }

    for (int k = 0; k < 256; k += 4) {
        float wreg[4][2];
        #pragma unroll
        for (int kk = 0; kk < 4; kk++) {
            float2 wv = *(const float2*)&W[(size_t)(k + kk) * 128 + cg * 2];
            wreg[kk][0] = wv.x; wreg[kk][1] = wv.y;
        }
        #pragma unroll
        for (int n = 0; n < 8; n++) {
            float4 f = *(const float4*)&l3s[ng * 8 + n][k];
            float fk[4] = { f.x, f.y, f.z, f.w };
            #pragma unroll
            for (int kk = 0; kk < 4; kk++) {
                acc2[n][0] = fmaf(fk[kk], wreg[kk][0], acc2[n][0]);
                acc2[n][1] = fmaf(fk[kk], wreg[kk][1], acc2[n][1]);
            }
        }
    }

    const float2 bv = *(const float2*)&b[cg * 2];
    #pragma unroll
    for (int n = 0; n < 8; n++) {
        float a0 = acc2[n][0] + bv.x, a1 = acc2[n][1] + bv.y;
        float d = wave_reduce_sum(a0 * a0 + a1 * a1);
        float norm = sqrtf(d);
        float nm = fmaxf(norm, EPSF);
        float se = tanhf(nm) / nm;
        const int node = n0 + ng * 8 + n;
        if (node < N_NODES) {
            float2 o; o.x = se * a0; o.y = se * a1;
            *(float2*)&out[(size_t)node * 128 + cg * 2] = o;
        }
    }
}

extern "C" void kernel_launch(void* const* d_in, const int* in_sizes, int n_in,
                              void* d_out, int out_size, void* d_ws, size_t ws_size,
                              hipStream_t stream) {
    const int*   x     = (const int*)  d_in[0];
    const float* emb0  = (const float*)d_in[1];
    const float* emb1  = (const float*)d_in[2];
    const float* emb2  = (const float*)d_in[3];
    const float* W_in  = (const float*)d_in[4];
    const float* b_in  = (const float*)d_in[5];
    const float* W_out = (const float*)d_in[6];
    const float* b_out = (const float*)d_in[7];
    const int*   src0  = (const int*)  d_in[8];
    const int*   src1  = (const int*)  d_in[10];
    float* out = (float*)d_out;

    ushort* l1 = (ushort*)d_ws;                           // 12.8M bf16 = 25.6 MB
    ushort* l2 = l1 + (size_t)N_NODES * 256;              // 25.6 MB
    float*  z2 = (float*)(l2 + (size_t)N_NODES * 256);    // 51.2 MB

    const int tiles = (N_NODES + 31) / 32;                // 1563

    k_encode_fc<<<tiles, 256, 0, stream>>>(x, emb0, emb1, emb2, W_in, b_in, l1);
    k_hat1<<<N_NODES / 4, 256, 0, stream>>>(l1, src0, l2);
    k_hat2<<<N_NODES / 4, 256, 0, stream>>>(l2, src1, z2);
    k_fc_out<<<tiles, 256, 0, stream>>>(z2, W_out, b_out, out);
}

// Round 3
// 222.278 us; speedup vs baseline: 1.7669x; 1.2964x over previous
//
#include <hip/hip_runtime.h>
#include <math.h>

#define N_NODES 50000
#define DEG 16
#define EPSF 1e-5f

typedef unsigned int uint;
typedef unsigned short ushort;

using bf16x8 = __attribute__((ext_vector_type(8))) short;
using f32x4  = __attribute__((ext_vector_type(4))) float;

__device__ __forceinline__ float wave_reduce_sum(float v) {
    #pragma unroll
    for (int off = 32; off >= 1; off >>= 1)
        v += __shfl_xor(v, off, 64);
    return v;
}
__device__ __forceinline__ float reduce32(float v) {
    #pragma unroll
    for (int off = 16; off >= 1; off >>= 1)
        v += __shfl_xor(v, off, 64);
    return v;
}

__device__ __forceinline__ float bf2f_lo(uint u) { return __uint_as_float(u << 16); }
__device__ __forceinline__ float bf2f_hi(uint u) { return __uint_as_float(u & 0xFFFF0000u); }
__device__ __forceinline__ uint  f2bf_rn(float f) {
    uint u = __float_as_uint(f);
    return (u + 0x7FFFu + ((u >> 16) & 1u)) >> 16;
}
__device__ __forceinline__ uint pack2(float a, float b) {
    return f2bf_rn(a) | (f2bf_rn(b) << 16);
}

// ---------------------------------------------------------------------------
// K0: weight prep: W_t[n][k] = bf16(W_in[k][n]), Wo_t[n][k] = bf16(W_out[k][n])
// ---------------------------------------------------------------------------
__global__ __launch_bounds__(256) void k_prep(
    const float* __restrict__ W_in, const float* __restrict__ W_out,
    ushort* __restrict__ W_t, ushort* __restrict__ Wo_t)
{
    const int b = blockIdx.x, t = threadIdx.x;
    if (b < 256) {
        W_t[b * 256 + t] = (ushort)f2bf_rn(W_in[t * 256 + b]);
    } else {
        const int n = b - 256;                      // 0..127
        Wo_t[n * 256 + t] = (ushort)f2bf_rn(W_out[t * 128 + n]);
    }
}

// ---------------------------------------------------------------------------
// K1: l1 = (feat @ W_in + b_in) in bf16 MFMA.  128 nodes/block, 4 waves,
// wave = 32 rows x 256 cols. A staged in XOR-swizzled LDS.
// ---------------------------------------------------------------------------
__global__ __launch_bounds__(256) void k_encode_mfma(
    const int* __restrict__ x,
    const float* __restrict__ emb0, const float* __restrict__ emb1,
    const float* __restrict__ emb2,
    const ushort* __restrict__ W_t, const float* __restrict__ b_in,
    ushort* __restrict__ l1)
{
    __shared__ ushort A[128 * 256];                 // 64 KB, swizzled
    const int t  = threadIdx.x;
    const int m0 = blockIdx.x * 128;

    // ---- stage: 4 iterations x (32 nodes x 8 segs of 32 floats) ----
    #pragma unroll
    for (int it = 0; it < 4; ++it) {
        const int nl   = it * 32 + (t >> 3);
        const int seg  = t & 7;
        const int node = m0 + nl;
        const int k0   = seg * 32;
        const float* p;
        if (node < N_NODES) {
            if (seg < 3)      p = emb0 + (size_t)x[node * 3 + 0] * 96 + k0;
            else if (seg < 6) p = emb1 + (size_t)x[node * 3 + 1] * 96 + (k0 - 96);
            else              p = emb2 + (size_t)x[node * 3 + 2] * 64 + (k0 - 192);
        } else {
            p = emb0;
        }
        const uint base = (uint)(nl * 512 + seg * 64);
        const uint sw   = (uint)((nl & 7) << 4);
        #pragma unroll
        for (int u = 0; u < 4; ++u) {
            float4 v0 = *(const float4*)(p + u * 8);
            float4 v1 = *(const float4*)(p + u * 8 + 4);
            uint4 pk;
            pk.x = pack2(v0.x, v0.y); pk.y = pack2(v0.z, v0.w);
            pk.z = pack2(v1.x, v1.y); pk.w = pack2(v1.z, v1.w);
            *(uint4*)((char*)A + ((base + u * 16) ^ sw)) = pk;
        }
    }
    __syncthreads();

    const int lane = t & 63;
    const int w    = t >> 6;
    const int l15  = lane & 15;
    const int lhi  = lane >> 4;

    f32x4 acc[2][16];
    #pragma unroll
    for (int rf = 0; rf < 2; ++rf)
        #pragma unroll
        for (int nf = 0; nf < 16; ++nf)
            acc[rf][nf] = (f32x4){0.f, 0.f, 0.f, 0.f};

    const ushort* Bp = W_t + (size_t)l15 * 256 + lhi * 8;
    const uint ar0 = (uint)((w * 32 + l15) * 512 + lhi * 16);
    const uint asw = (uint)((l15 & 7) << 4);

    for (int kk = 0; kk < 8; ++kk) {
        bf16x8 a0 = *(const bf16x8*)((const char*)A + ((ar0 + kk * 64) ^ asw));
        bf16x8 a1 = *(const bf16x8*)((const char*)A + ((ar0 + 16 * 512 + kk * 64) ^ asw));
        #pragma unroll
        for (int nf = 0; nf < 16; ++nf) {
            bf16x8 bfr = *(const bf16x8*)(Bp + (size_t)nf * 16 * 256 + kk * 32);
            acc[0][nf] = __builtin_amdgcn_mfma_f32_16x16x32_bf16(a0, bfr, acc[0][nf], 0, 0, 0);
            acc[1][nf] = __builtin_amdgcn_mfma_f32_16x16x32_bf16(a1, bfr, acc[1][nf], 0, 0, 0);
        }
    }

    // ---- epilogue: + bias, cast bf16, store ----
    #pragma unroll
    for (int rf = 0; rf < 2; ++rf) {
        const int rbase = m0 + w * 32 + rf * 16 + lhi * 4;
        #pragma unroll
        for (int nf = 0; nf < 16; ++nf) {
            const int col = nf * 16 + l15;
            const float bias = b_in[col];
            #pragma unroll
            for (int r = 0; r < 4; ++r) {
                const int node = rbase + r;
                if (node < N_NODES)
                    l1[(size_t)node * 256 + col] = (ushort)f2bf_rn(acc[rf][nf][r] + bias);
            }
        }
    }
}

// ---------------------------------------------------------------------------
// K2: z = mean_17(l1 rows); h = relu(exp0(z)); l2 = log0(h)   (bf16 -> bf16)
// ---------------------------------------------------------------------------
__global__ __launch_bounds__(256) void k_hat1(
    const ushort* __restrict__ lin, const int* __restrict__ src,
    ushort* __restrict__ lout)
{
    const int lane = threadIdx.x & 63;
    const int half = lane >> 5;
    const int li   = lane & 31;
    const int v    = blockIdx.x * 4 + (threadIdx.x >> 6);
    const int vv   = __builtin_amdgcn_readfirstlane(v);

    const int* sp = src + (size_t)vv * DEG;
    const size_t cb = (size_t)li << 4;

    uint4 r[8];
    #pragma unroll
    for (int j = 0; j < 8; j++) {
        int s0 = sp[j];
        int s1 = sp[j + 8];
        size_t sidx = (size_t)(half ? s1 : s0);
        r[j] = *(const uint4*)((const char*)lin + (sidx << 9) + cb);
    }

    float acc[8];
    #pragma unroll
    for (int i = 0; i < 8; i++) acc[i] = 0.f;
    #pragma unroll
    for (int j = 0; j < 8; j++) {
        acc[0] += bf2f_lo(r[j].x); acc[1] += bf2f_hi(r[j].x);
        acc[2] += bf2f_lo(r[j].y); acc[3] += bf2f_hi(r[j].y);
        acc[4] += bf2f_lo(r[j].z); acc[5] += bf2f_hi(r[j].z);
        acc[6] += bf2f_lo(r[j].w); acc[7] += bf2f_hi(r[j].w);
    }
    if (half == 0) {
        uint4 rs = *(const uint4*)((const char*)lin + ((size_t)vv << 9) + cb);
        acc[0] += bf2f_lo(rs.x); acc[1] += bf2f_hi(rs.x);
        acc[2] += bf2f_lo(rs.y); acc[3] += bf2f_hi(rs.y);
        acc[4] += bf2f_lo(rs.z); acc[5] += bf2f_hi(rs.z);
        acc[6] += bf2f_lo(rs.w); acc[7] += bf2f_hi(rs.w);
    }
    #pragma unroll
    for (int i = 0; i < 8; i++)
        acc[i] += __shfl_xor(acc[i], 32, 64);

    const float inv = 1.f / (float)(DEG + 1);
    float z[8], ss = 0.f;
    #pragma unroll
    for (int i = 0; i < 8; i++) { z[i] = acc[i] * inv; ss += z[i] * z[i]; }
    float d = reduce32(ss);
    float norm = sqrtf(d);
    float nm = fmaxf(norm, EPSF);
    float se = tanhf(nm) / nm;

    float h[8], s2s = 0.f;
    #pragma unroll
    for (int i = 0; i < 8; i++) { h[i] = fmaxf(se * z[i], 0.f); s2s += h[i] * h[i]; }
    float nh = sqrtf(reduce32(s2s));
    float nc = fminf(fmaxf(nh, EPSF), 1.f - EPSF);
    float s2 = atanhf(nc) / nc;

    uint p0 = pack2(s2 * h[0], s2 * h[1]);
    uint p1 = pack2(s2 * h[2], s2 * h[3]);
    uint p2 = pack2(s2 * h[4], s2 * h[5]);
    uint p3 = pack2(s2 * h[6], s2 * h[7]);
    uint2 u = half ? make_uint2(p2, p3) : make_uint2(p0, p1);
    *(uint2*)((char*)lout + ((size_t)vv << 9) + (li << 4) + (half << 3)) = u;
}

// ---------------------------------------------------------------------------
// K3: z2 = mean_17(l2 rows) -> bf16  (log0(exp0(z2)) identity)
// ---------------------------------------------------------------------------
__global__ __launch_bounds__(256) void k_hat2(
    const ushort* __restrict__ lin, const int* __restrict__ src,
    ushort* __restrict__ z2b)
{
    const int lane = threadIdx.x & 63;
    const int half = lane >> 5;
    const int li   = lane & 31;
    const int v    = blockIdx.x * 4 + (threadIdx.x >> 6);
    const int vv   = __builtin_amdgcn_readfirstlane(v);

    const int* sp = src + (size_t)vv * DEG;
    const size_t cb = (size_t)li << 4;

    uint4 r[8];
    #pragma unroll
    for (int j = 0; j < 8; j++) {
        int s0 = sp[j];
        int s1 = sp[j + 8];
        size_t sidx = (size_t)(half ? s1 : s0);
        r[j] = *(const uint4*)((const char*)lin + (sidx << 9) + cb);
    }

    float acc[8];
    #pragma unroll
    for (int i = 0; i < 8; i++) acc[i] = 0.f;
    #pragma unroll
    for (int j = 0; j < 8; j++) {
        acc[0] += bf2f_lo(r[j].x); acc[1] += bf2f_hi(r[j].x);
        acc[2] += bf2f_lo(r[j].y); acc[3] += bf2f_hi(r[j].y);
        acc[4] += bf2f_lo(r[j].z); acc[5] += bf2f_hi(r[j].z);
        acc[6] += bf2f_lo(r[j].w); acc[7] += bf2f_hi(r[j].w);
    }
    if (half == 0) {
        uint4 rs = *(const uint4*)((const char*)lin + ((size_t)vv << 9) + cb);
        acc[0] += bf2f_lo(rs.x); acc[1] += bf2f_hi(rs.x);
        acc[2] += bf2f_lo(rs.y); acc[3] += bf2f_hi(rs.y);
        acc[4] += bf2f_lo(rs.z); acc[5] += bf2f_hi(rs.z);
        acc[6] += bf2f_lo(rs.w); acc[7] += bf2f_hi(rs.w);
    }
    #pragma unroll
    for (int i = 0; i < 8; i++)
        acc[i] += __shfl_xor(acc[i], 32, 64);

    const float inv = 1.f / (float)(DEG + 1);
    uint2 u;
    if (half == 0)
        u = make_uint2(pack2(acc[0] * inv, acc[1] * inv), pack2(acc[2] * inv, acc[3] * inv));
    else
        u = make_uint2(pack2(acc[4] * inv, acc[5] * inv), pack2(acc[6] * inv, acc[7] * inv));
    *(uint2*)((char*)z2b + ((size_t)vv << 9) + (li << 4) + (half << 3)) = u;
}

// ---------------------------------------------------------------------------
// K4: out = exp0(z2 @ W_out + b_out) in bf16 MFMA.  128 nodes/block, 4 waves,
// wave = 32 rows x 128 cols. A read straight from global (contiguous rows).
// ---------------------------------------------------------------------------
__global__ __launch_bounds__(256) void k_fc_out_mfma(
    const ushort* __restrict__ z2b, const ushort* __restrict__ Wo_t,
    const float* __restrict__ b_out, float* __restrict__ out)
{
    const int t    = threadIdx.x;
    const int lane = t & 63;
    const int w    = t >> 6;
    const int l15  = lane & 15;
    const int lhi  = lane >> 4;
    const int m0   = blockIdx.x * 128;

    f32x4 acc[2][8];
    #pragma unroll
    for (int rf = 0; rf < 2; ++rf)
        #pragma unroll
        for (int nf = 0; nf < 8; ++nf)
            acc[rf][nf] = (f32x4){0.f, 0.f, 0.f, 0.f};

    const ushort* Ap = z2b + (size_t)(m0 + w * 32 + l15) * 256 + lhi * 8;
    const ushort* Bp = Wo_t + (size_t)l15 * 256 + lhi * 8;

    for (int kk = 0; kk < 8; ++kk) {
        bf16x8 a0 = *(const bf16x8*)(Ap + kk * 32);
        bf16x8 a1 = *(const bf16x8*)(Ap + 16 * 256 + kk * 32);
        #pragma unroll
        for (int nf = 0; nf < 8; ++nf) {
            bf16x8 bfr = *(const bf16x8*)(Bp + (size_t)nf * 16 * 256 + kk * 32);
            acc[0][nf] = __builtin_amdgcn_mfma_f32_16x16x32_bf16(a0, bfr, acc[0][nf], 0, 0, 0);
            acc[1][nf] = __builtin_amdgcn_mfma_f32_16x16x32_bf16(a1, bfr, acc[1][nf], 0, 0, 0);
        }
    }

    // bias (b_out) then exp0 per row
    float bias[8];
    #pragma unroll
    for (int nf = 0; nf < 8; ++nf) bias[nf] = b_out[nf * 16 + l15];

    #pragma unroll
    for (int rf = 0; rf < 2; ++rf) {
        float ssr[4] = {0.f, 0.f, 0.f, 0.f};
        #pragma unroll
        for (int nf = 0; nf < 8; ++nf) {
            #pragma unroll
            for (int r = 0; r < 4; ++r) {
                float tv = acc[rf][nf][r] + bias[nf];
                acc[rf][nf][r] = tv;
                ssr[r] += tv * tv;
            }
        }
        #pragma unroll
        for (int r = 0; r < 4; ++r) {
            #pragma unroll
            for (int off = 1; off <= 8; off <<= 1)
                ssr[r] += __shfl_xor(ssr[r], off, 64);
        }
        float se[4];
        #pragma unroll
        for (int r = 0; r < 4; ++r) {
            float norm = sqrtf(ssr[r]);
            float nm = fmaxf(norm, EPSF);
            se[r] = tanhf(nm) / nm;
        }
        const int rbase = m0 + w * 32 + rf * 16 + lhi * 4;
        #pragma unroll
        for (int nf = 0; nf < 8; ++nf) {
            #pragma unroll
            for (int r = 0; r < 4; ++r) {
                const int node = rbase + r;
                if (node < N_NODES)
                    out[(size_t)node * 128 + nf * 16 + l15] = se[r] * acc[rf][nf][r];
            }
        }
    }
}

extern "C" void kernel_launch(void* const* d_in, const int* in_sizes, int n_in,
                              void* d_out, int out_size, void* d_ws, size_t ws_size,
                              hipStream_t stream) {
    const int*   x     = (const int*)  d_in[0];
    const float* emb0  = (const float*)d_in[1];
    const float* emb1  = (const float*)d_in[2];
    const float* emb2  = (const float*)d_in[3];
    const float* W_in  = (const float*)d_in[4];
    const float* b_in  = (const float*)d_in[5];
    const float* W_out = (const float*)d_in[6];
    const float* b_out = (const float*)d_in[7];
    const int*   src0  = (const int*)  d_in[8];
    const int*   src1  = (const int*)  d_in[10];
    float* out = (float*)d_out;

    ushort* l1  = (ushort*)d_ws;                          // 25.6 MB
    ushort* l2  = l1 + (size_t)N_NODES * 256;             // 25.6 MB
    ushort* z2b = l2 + (size_t)N_NODES * 256;             // 25.6 MB
    ushort* W_t = z2b + (size_t)N_NODES * 256;            // 128 KB
    ushort* Wo_t = W_t + 256 * 256;                       // 64 KB

    const int mtiles = (N_NODES + 127) / 128;             // 391

    k_prep<<<384, 256, 0, stream>>>(W_in, W_out, W_t, Wo_t);
    k_encode_mfma<<<mtiles, 256, 0, stream>>>(x, emb0, emb1, emb2, W_t, b_in, l1);
    k_hat1<<<N_NODES / 4, 256, 0, stream>>>(l1, src0, l2);
    k_hat2<<<N_NODES / 4, 256, 0, stream>>>(l2, src1, z2b);
    k_fc_out_mfma<<<mtiles, 256, 0, stream>>>(z2b, Wo_t, b_out, out);
}

// Round 4
// 185.337 us; speedup vs baseline: 2.1191x; 1.1993x over previous
//
#include <hip/hip_runtime.h>
#include <math.h>

#define N_NODES 50000
#define DEG 16
#define EPSF 1e-5f

typedef unsigned int uint;
typedef unsigned short ushort;

using bf16x8 = __attribute__((ext_vector_type(8))) short;
using f32x4  = __attribute__((ext_vector_type(4))) float;

__device__ __forceinline__ float reduce32(float v) {
    #pragma unroll
    for (int off = 16; off >= 1; off >>= 1)
        v += __shfl_xor(v, off, 64);
    return v;
}

__device__ __forceinline__ float bf2f_lo(uint u) { return __uint_as_float(u << 16); }
__device__ __forceinline__ float bf2f_hi(uint u) { return __uint_as_float(u & 0xFFFF0000u); }
__device__ __forceinline__ uint  f2bf_rn(float f) {
    uint u = __float_as_uint(f);
    return (u + 0x7FFFu + ((u >> 16) & 1u)) >> 16;
}
__device__ __forceinline__ uint pack2(float a, float b) {
    return f2bf_rn(a) | (f2bf_rn(b) << 16);
}

// ---------------------------------------------------------------------------
// K0: weight prep: W_t[n][k] = bf16(W_in[k][n]), Wo_t[n][k] = bf16(W_out[k][n])
// ---------------------------------------------------------------------------
__global__ __launch_bounds__(256) void k_prep(
    const float* __restrict__ W_in, const float* __restrict__ W_out,
    ushort* __restrict__ W_t, ushort* __restrict__ Wo_t)
{
    const int b = blockIdx.x, t = threadIdx.x;
    if (b < 256) {
        W_t[b * 256 + t] = (ushort)f2bf_rn(W_in[t * 256 + b]);
    } else {
        const int n = b - 256;
        Wo_t[n * 256 + t] = (ushort)f2bf_rn(W_out[t * 128 + n]);
    }
}

// ---------------------------------------------------------------------------
// K1: l1 = feat @ W_in + b_in  (bf16 MFMA, swapped operands).
// Block: 256 thr / 4 waves; tile 64 rows x 256 cols; wave = 64 rows x 64 cols.
// acc[4 rf][4 nf] = 64 VGPR. A staged in XOR-swizzled LDS (32 KB).
// Swapped mfma(W, feat): D reg r -> col n+r, lane&15 -> row m.
// ---------------------------------------------------------------------------
__global__ __launch_bounds__(256) void k_encode_mfma(
    const int* __restrict__ x,
    const float* __restrict__ emb0, const float* __restrict__ emb1,
    const float* __restrict__ emb2,
    const ushort* __restrict__ W_t, const float* __restrict__ b_in,
    ushort* __restrict__ l1)
{
    __shared__ ushort A[64 * 256];                  // 32 KB, swizzled
    const int t  = threadIdx.x;
    const int m0 = blockIdx.x * 64;

    #pragma unroll
    for (int it = 0; it < 2; ++it) {
        const int nl   = it * 32 + (t >> 3);
        const int seg  = t & 7;
        const int node = m0 + nl;
        const int k0   = seg * 32;
        const float* p;
        if (node < N_NODES) {
            if (seg < 3)      p = emb0 + (size_t)x[node * 3 + 0] * 96 + k0;
            else if (seg < 6) p = emb1 + (size_t)x[node * 3 + 1] * 96 + (k0 - 96);
            else              p = emb2 + (size_t)x[node * 3 + 2] * 64 + (k0 - 192);
        } else {
            p = emb0;
        }
        const uint base = (uint)(nl * 512 + seg * 64);
        const uint sw   = (uint)((nl & 7) << 4);
        #pragma unroll
        for (int u = 0; u < 4; ++u) {
            float4 v0 = *(const float4*)(p + u * 8);
            float4 v1 = *(const float4*)(p + u * 8 + 4);
            uint4 pk;
            pk.x = pack2(v0.x, v0.y); pk.y = pack2(v0.z, v0.w);
            pk.z = pack2(v1.x, v1.y); pk.w = pack2(v1.z, v1.w);
            *(uint4*)((char*)A + ((base + u * 16) ^ sw)) = pk;
        }
    }
    __syncthreads();

    const int lane = t & 63;
    const int w    = t >> 6;          // col-slice: cols w*64 .. w*64+63
    const int l15  = lane & 15;
    const int lhi  = lane >> 4;

    f32x4 acc[4][4];
    #pragma unroll
    for (int rf = 0; rf < 4; ++rf)
        #pragma unroll
        for (int nf = 0; nf < 4; ++nf)
            acc[rf][nf] = (f32x4){0.f, 0.f, 0.f, 0.f};

    const ushort* Wp = W_t + (size_t)(w * 64 + l15) * 256 + lhi * 8;
    const uint asw = (uint)((l15 & 7) << 4);

    for (int kk = 0; kk < 8; ++kk) {
        bf16x8 f[4];
        #pragma unroll
        for (int rf = 0; rf < 4; ++rf) {
            const uint ad = (uint)((rf * 16 + l15) * 512 + lhi * 16 + kk * 64);
            f[rf] = *(const bf16x8*)((const char*)A + (ad ^ asw));
        }
        #pragma unroll
        for (int nf = 0; nf < 4; ++nf) {
            bf16x8 wv = *(const bf16x8*)(Wp + (size_t)nf * 16 * 256 + kk * 32);
            #pragma unroll
            for (int rf = 0; rf < 4; ++rf)
                acc[rf][nf] = __builtin_amdgcn_mfma_f32_16x16x32_bf16(wv, f[rf], acc[rf][nf], 0, 0, 0);
        }
    }

    #pragma unroll
    for (int rf = 0; rf < 4; ++rf) {
        const int m = m0 + rf * 16 + l15;
        if (m < N_NODES) {
            #pragma unroll
            for (int nf = 0; nf < 4; ++nf) {
                const int n = w * 64 + nf * 16 + lhi * 4;
                float4 bb = *(const float4*)&b_in[n];
                uint2 pk;
                pk.x = pack2(acc[rf][nf][0] + bb.x, acc[rf][nf][1] + bb.y);
                pk.y = pack2(acc[rf][nf][2] + bb.z, acc[rf][nf][3] + bb.w);
                *(uint2*)&l1[(size_t)m * 256 + n] = pk;
            }
        }
    }
}

// ---------------------------------------------------------------------------
// K2: z = mean_17(l1 rows); h = relu(exp0(z)); l2 = log0(h)   (bf16 -> bf16)
// ---------------------------------------------------------------------------
__global__ __launch_bounds__(256) void k_hat1(
    const ushort* __restrict__ lin, const int* __restrict__ src,
    ushort* __restrict__ lout)
{
    const int lane = threadIdx.x & 63;
    const int half = lane >> 5;
    const int li   = lane & 31;
    const int v    = blockIdx.x * 4 + (threadIdx.x >> 6);
    const int vv   = __builtin_amdgcn_readfirstlane(v);

    const int* sp = src + (size_t)vv * DEG;
    const size_t cb = (size_t)li << 4;

    uint4 r[8];
    #pragma unroll
    for (int j = 0; j < 8; j++) {
        int s0 = sp[j];
        int s1 = sp[j + 8];
        size_t sidx = (size_t)(half ? s1 : s0);
        r[j] = *(const uint4*)((const char*)lin + (sidx << 9) + cb);
    }

    float acc[8];
    #pragma unroll
    for (int i = 0; i < 8; i++) acc[i] = 0.f;
    #pragma unroll
    for (int j = 0; j < 8; j++) {
        acc[0] += bf2f_lo(r[j].x); acc[1] += bf2f_hi(r[j].x);
        acc[2] += bf2f_lo(r[j].y); acc[3] += bf2f_hi(r[j].y);
        acc[4] += bf2f_lo(r[j].z); acc[5] += bf2f_hi(r[j].z);
        acc[6] += bf2f_lo(r[j].w); acc[7] += bf2f_hi(r[j].w);
    }
    if (half == 0) {
        uint4 rs = *(const uint4*)((const char*)lin + ((size_t)vv << 9) + cb);
        acc[0] += bf2f_lo(rs.x); acc[1] += bf2f_hi(rs.x);
        acc[2] += bf2f_lo(rs.y); acc[3] += bf2f_hi(rs.y);
        acc[4] += bf2f_lo(rs.z); acc[5] += bf2f_hi(rs.z);
        acc[6] += bf2f_lo(rs.w); acc[7] += bf2f_hi(rs.w);
    }
    #pragma unroll
    for (int i = 0; i < 8; i++)
        acc[i] += __shfl_xor(acc[i], 32, 64);

    const float inv = 1.f / (float)(DEG + 1);
    float z[8], ss = 0.f;
    #pragma unroll
    for (int i = 0; i < 8; i++) { z[i] = acc[i] * inv; ss += z[i] * z[i]; }
    float d = reduce32(ss);
    float norm = sqrtf(d);
    float nm = fmaxf(norm, EPSF);
    float se = tanhf(nm) / nm;

    float h[8], s2s = 0.f;
    #pragma unroll
    for (int i = 0; i < 8; i++) { h[i] = fmaxf(se * z[i], 0.f); s2s += h[i] * h[i]; }
    float nh = sqrtf(reduce32(s2s));
    float nc = fminf(fmaxf(nh, EPSF), 1.f - EPSF);
    float s2 = atanhf(nc) / nc;

    uint p0 = pack2(s2 * h[0], s2 * h[1]);
    uint p1 = pack2(s2 * h[2], s2 * h[3]);
    uint p2 = pack2(s2 * h[4], s2 * h[5]);
    uint p3 = pack2(s2 * h[6], s2 * h[7]);
    uint2 u = half ? make_uint2(p2, p3) : make_uint2(p0, p1);
    *(uint2*)((char*)lout + ((size_t)vv << 9) + (li << 4) + (half << 3)) = u;
}

// ---------------------------------------------------------------------------
// K3: z2 = mean_17(l2 rows) -> bf16  (log0(exp0(z2)) identity)
// ---------------------------------------------------------------------------
__global__ __launch_bounds__(256) void k_hat2(
    const ushort* __restrict__ lin, const int* __restrict__ src,
    ushort* __restrict__ z2b)
{
    const int lane = threadIdx.x & 63;
    const int half = lane >> 5;
    const int li   = lane & 31;
    const int v    = blockIdx.x * 4 + (threadIdx.x >> 6);
    const int vv   = __builtin_amdgcn_readfirstlane(v);

    const int* sp = src + (size_t)vv * DEG;
    const size_t cb = (size_t)li << 4;

    uint4 r[8];
    #pragma unroll
    for (int j = 0; j < 8; j++) {
        int s0 = sp[j];
        int s1 = sp[j + 8];
        size_t sidx = (size_t)(half ? s1 : s0);
        r[j] = *(const uint4*)((const char*)lin + (sidx << 9) + cb);
    }

    float acc[8];
    #pragma unroll
    for (int i = 0; i < 8; i++) acc[i] = 0.f;
    #pragma unroll
    for (int j = 0; j < 8; j++) {
        acc[0] += bf2f_lo(r[j].x); acc[1] += bf2f_hi(r[j].x);
        acc[2] += bf2f_lo(r[j].y); acc[3] += bf2f_hi(r[j].y);
        acc[4] += bf2f_lo(r[j].z); acc[5] += bf2f_hi(r[j].z);
        acc[6] += bf2f_lo(r[j].w); acc[7] += bf2f_hi(r[j].w);
    }
    if (half == 0) {
        uint4 rs = *(const uint4*)((const char*)lin + ((size_t)vv << 9) + cb);
        acc[0] += bf2f_lo(rs.x); acc[1] += bf2f_hi(rs.x);
        acc[2] += bf2f_lo(rs.y); acc[3] += bf2f_hi(rs.y);
        acc[4] += bf2f_lo(rs.z); acc[5] += bf2f_hi(rs.z);
        acc[6] += bf2f_lo(rs.w); acc[7] += bf2f_hi(rs.w);
    }
    #pragma unroll
    for (int i = 0; i < 8; i++)
        acc[i] += __shfl_xor(acc[i], 32, 64);

    const float inv = 1.f / (float)(DEG + 1);
    uint2 u;
    if (half == 0)
        u = make_uint2(pack2(acc[0] * inv, acc[1] * inv), pack2(acc[2] * inv, acc[3] * inv));
    else
        u = make_uint2(pack2(acc[4] * inv, acc[5] * inv), pack2(acc[6] * inv, acc[7] * inv));
    *(uint2*)((char*)z2b + ((size_t)vv << 9) + (li << 4) + (half << 3)) = u;
}

// ---------------------------------------------------------------------------
// K4: out = exp0(z2 @ W_out + b_out)  (bf16 MFMA, swapped operands).
// Block: 256 thr / 4 waves; 128 rows; wave = 32 rows x 128 cols, acc[2][8].
// Swapped layout: lane&15 -> row m; reg r -> col n+r  => float4 stores,
// row-norm reduce = shfl_xor(16) + shfl_xor(32).
// ---------------------------------------------------------------------------
__global__ __launch_bounds__(256) void k_fc_out_mfma(
    const ushort* __restrict__ z2b, const ushort* __restrict__ Wo_t,
    const float* __restrict__ b_out, float* __restrict__ out)
{
    const int t    = threadIdx.x;
    const int lane = t & 63;
    const int w    = t >> 6;
    const int l15  = lane & 15;
    const int lhi  = lane >> 4;
    const int m0   = blockIdx.x * 128;

    f32x4 acc[2][8];
    #pragma unroll
    for (int rf = 0; rf < 2; ++rf)
        #pragma unroll
        for (int nf = 0; nf < 8; ++nf)
            acc[rf][nf] = (f32x4){0.f, 0.f, 0.f, 0.f};

    const ushort* Ap = z2b + (size_t)(m0 + w * 32 + l15) * 256 + lhi * 8;
    const ushort* Wp = Wo_t + (size_t)l15 * 256 + lhi * 8;

    for (int kk = 0; kk < 8; ++kk) {
        bf16x8 f0 = *(const bf16x8*)(Ap + kk * 32);
        bf16x8 f1 = *(const bf16x8*)(Ap + 16 * 256 + kk * 32);
        #pragma unroll
        for (int nf = 0; nf < 8; ++nf) {
            bf16x8 wv = *(const bf16x8*)(Wp + (size_t)nf * 16 * 256 + kk * 32);
            acc[0][nf] = __builtin_amdgcn_mfma_f32_16x16x32_bf16(wv, f0, acc[0][nf], 0, 0, 0);
            acc[1][nf] = __builtin_amdgcn_mfma_f32_16x16x32_bf16(wv, f1, acc[1][nf], 0, 0, 0);
        }
    }

    float4 bb[8];
    #pragma unroll
    for (int nf = 0; nf < 8; ++nf)
        bb[nf] = *(const float4*)&b_out[nf * 16 + lhi * 4];

    #pragma unroll
    for (int rf = 0; rf < 2; ++rf) {
        const int m = m0 + w * 32 + rf * 16 + l15;
        float ss = 0.f;
        #pragma unroll
        for (int nf = 0; nf < 8; ++nf) {
            float t0 = acc[rf][nf][0] + bb[nf].x;
            float t1 = acc[rf][nf][1] + bb[nf].y;
            float t2 = acc[rf][nf][2] + bb[nf].z;
            float t3 = acc[rf][nf][3] + bb[nf].w;
            acc[rf][nf][0] = t0; acc[rf][nf][1] = t1;
            acc[rf][nf][2] = t2; acc[rf][nf][3] = t3;
            ss += t0 * t0 + t1 * t1 + t2 * t2 + t3 * t3;
        }
        ss += __shfl_xor(ss, 16, 64);
        ss += __shfl_xor(ss, 32, 64);
        float norm = sqrtf(ss);
        float nm = fmaxf(norm, EPSF);
        float se = tanhf(nm) / nm;
        if (m < N_NODES) {
            #pragma unroll
            for (int nf = 0; nf < 8; ++nf) {
                float4 o;
                o.x = se * acc[rf][nf][0];
                o.y = se * acc[rf][nf][1];
                o.z = se * acc[rf][nf][2];
                o.w = se * acc[rf][nf][3];
                *(float4*)&out[(size_t)m * 128 + nf * 16 + lhi * 4] = o;
            }
        }
    }
}

extern "C" void kernel_launch(void* const* d_in, const int* in_sizes, int n_in,
                              void* d_out, int out_size, void* d_ws, size_t ws_size,
                              hipStream_t stream) {
    const int*   x     = (const int*)  d_in[0];
    const float* emb0  = (const float*)d_in[1];
    const float* emb1  = (const float*)d_in[2];
    const float* emb2  = (const float*)d_in[3];
    const float* W_in  = (const float*)d_in[4];
    const float* b_in  = (const float*)d_in[5];
    const float* W_out = (const float*)d_in[6];
    const float* b_out = (const float*)d_in[7];
    const int*   src0  = (const int*)  d_in[8];
    const int*   src1  = (const int*)  d_in[10];
    float* out = (float*)d_out;

    ushort* l1  = (ushort*)d_ws;                          // 25.6 MB
    ushort* l2  = l1 + (size_t)N_NODES * 256;             // 25.6 MB
    ushort* z2b = l2 + (size_t)N_NODES * 256;             // 25.6 MB
    ushort* W_t = z2b + (size_t)N_NODES * 256;            // 128 KB
    ushort* Wo_t = W_t + 256 * 256;                       // 64 KB

    k_prep<<<384, 256, 0, stream>>>(W_in, W_out, W_t, Wo_t);
    k_encode_mfma<<<(N_NODES + 63) / 64, 256, 0, stream>>>(x, emb0, emb1, emb2, W_t, b_in, l1);
    k_hat1<<<N_NODES / 4, 256, 0, stream>>>(l1, src0, l2);
    k_hat2<<<N_NODES / 4, 256, 0, stream>>>(l2, src1, z2b);
    k_fc_out_mfma<<<(N_NODES + 127) / 128, 256, 0, stream>>>(z2b, Wo_t, b_out, out);
}

// Round 5
// 182.951 us; speedup vs baseline: 2.1467x; 1.0130x over previous
//
#include <hip/hip_runtime.h>
#include <math.h>

#define N_NODES 50000
#define DEG 16
#define EPSF 1e-5f

typedef unsigned int uint;
typedef unsigned short ushort;

using bf16x8 = __attribute__((ext_vector_type(8))) short;
using f32x4  = __attribute__((ext_vector_type(4))) float;

__device__ __forceinline__ float bf2f_lo(uint u) { return __uint_as_float(u << 16); }
__device__ __forceinline__ float bf2f_hi(uint u) { return __uint_as_float(u & 0xFFFF0000u); }
__device__ __forceinline__ uint  f2bf_rn(float f) {
    uint u = __float_as_uint(f);
    return (u + 0x7FFFu + ((u >> 16) & 1u)) >> 16;
}
__device__ __forceinline__ uint pack2(float a, float b) {
    return f2bf_rn(a) | (f2bf_rn(b) << 16);
}

// ---- VALU-only wave reductions --------------------------------------------
// sum of v and v[lane^32] (both halves get total)
__device__ __forceinline__ float pl32_sum(float v) {
#if __has_builtin(__builtin_amdgcn_permlane32_swap)
    auto r = __builtin_amdgcn_permlane32_swap((int)__float_as_uint(v), (int)__float_as_uint(v), false, false);
    return __uint_as_float((uint)r[0]) + __uint_as_float((uint)r[1]);
#else
    return v + __shfl_xor(v, 32, 64);
#endif
}
__device__ __forceinline__ float pl16_sum(float v) {
#if __has_builtin(__builtin_amdgcn_permlane16_swap)
    auto r = __builtin_amdgcn_permlane16_swap((int)__float_as_uint(v), (int)__float_as_uint(v), false, false);
    return __uint_as_float((uint)r[0]) + __uint_as_float((uint)r[1]);
#else
    return v + __shfl_xor(v, 16, 64);
#endif
}
#define DPP_ROR_ADD(v, CTRL) \
    v += __uint_as_float((uint)__builtin_amdgcn_update_dpp(0, (int)__float_as_uint(v), (CTRL), 0xF, 0xF, false))

// sum over each 32-lane half (row_ror 1,2,4,8 within 16 + permlane16 swap)
__device__ __forceinline__ float red32(float v) {
    DPP_ROR_ADD(v, 0x121);
    DPP_ROR_ADD(v, 0x122);
    DPP_ROR_ADD(v, 0x124);
    DPP_ROR_ADD(v, 0x128);
    return pl16_sum(v);
}

// ---- fast hyperbolic helpers ----------------------------------------------
__device__ __forceinline__ float tanh_over_x(float nm) {      // tanh(nm)/nm, nm>0
    float e = __expf(2.f * nm);
    float t = 1.f - __fdividef(2.f, e + 1.f);
    return __fdividef(t, nm);
}
__device__ __forceinline__ float atanh_over_x(float n) {      // atanh(n)/n, 0<n<1
    float l = __logf(__fdividef(1.f + n, 1.f - n));
    return 0.5f * __fdividef(l, n);
}

// ---------------------------------------------------------------------------
// K0: weight prep: W_t[n][k] = bf16(W_in[k][n]), Wo_t[n][k] = bf16(W_out[k][n])
// ---------------------------------------------------------------------------
__global__ __launch_bounds__(256) void k_prep(
    const float* __restrict__ W_in, const float* __restrict__ W_out,
    ushort* __restrict__ W_t, ushort* __restrict__ Wo_t)
{
    const int b = blockIdx.x, t = threadIdx.x;
    if (b < 256) {
        W_t[b * 256 + t] = (ushort)f2bf_rn(W_in[t * 256 + b]);
    } else {
        const int n = b - 256;
        Wo_t[n * 256 + t] = (ushort)f2bf_rn(W_out[t * 128 + n]);
    }
}

// ---------------------------------------------------------------------------
// K1: l1 = feat @ W_in + b_in  (bf16 MFMA, swapped operands).
// ---------------------------------------------------------------------------
__global__ __launch_bounds__(256) void k_encode_mfma(
    const int* __restrict__ x,
    const float* __restrict__ emb0, const float* __restrict__ emb1,
    const float* __restrict__ emb2,
    const ushort* __restrict__ W_t, const float* __restrict__ b_in,
    ushort* __restrict__ l1)
{
    __shared__ ushort A[64 * 256];                  // 32 KB, swizzled
    const int t  = threadIdx.x;
    const int m0 = blockIdx.x * 64;

    #pragma unroll
    for (int it = 0; it < 2; ++it) {
        const int nl   = it * 32 + (t >> 3);
        const int seg  = t & 7;
        const int node = m0 + nl;
        const int k0   = seg * 32;
        const float* p;
        if (node < N_NODES) {
            if (seg < 3)      p = emb0 + (size_t)x[node * 3 + 0] * 96 + k0;
            else if (seg < 6) p = emb1 + (size_t)x[node * 3 + 1] * 96 + (k0 - 96);
            else              p = emb2 + (size_t)x[node * 3 + 2] * 64 + (k0 - 192);
        } else {
            p = emb0;
        }
        const uint base = (uint)(nl * 512 + seg * 64);
        const uint sw   = (uint)((nl & 7) << 4);
        #pragma unroll
        for (int u = 0; u < 4; ++u) {
            float4 v0 = *(const float4*)(p + u * 8);
            float4 v1 = *(const float4*)(p + u * 8 + 4);
            uint4 pk;
            pk.x = pack2(v0.x, v0.y); pk.y = pack2(v0.z, v0.w);
            pk.z = pack2(v1.x, v1.y); pk.w = pack2(v1.z, v1.w);
            *(uint4*)((char*)A + ((base + u * 16) ^ sw)) = pk;
        }
    }
    __syncthreads();

    const int lane = t & 63;
    const int w    = t >> 6;
    const int l15  = lane & 15;
    const int lhi  = lane >> 4;

    f32x4 acc[4][4];
    #pragma unroll
    for (int rf = 0; rf < 4; ++rf)
        #pragma unroll
        for (int nf = 0; nf < 4; ++nf)
            acc[rf][nf] = (f32x4){0.f, 0.f, 0.f, 0.f};

    const ushort* Wp = W_t + (size_t)(w * 64 + l15) * 256 + lhi * 8;
    const uint asw = (uint)((l15 & 7) << 4);

    for (int kk = 0; kk < 8; ++kk) {
        bf16x8 f[4];
        #pragma unroll
        for (int rf = 0; rf < 4; ++rf) {
            const uint ad = (uint)((rf * 16 + l15) * 512 + lhi * 16 + kk * 64);
            f[rf] = *(const bf16x8*)((const char*)A + (ad ^ asw));
        }
        #pragma unroll
        for (int nf = 0; nf < 4; ++nf) {
            bf16x8 wv = *(const bf16x8*)(Wp + (size_t)nf * 16 * 256 + kk * 32);
            #pragma unroll
            for (int rf = 0; rf < 4; ++rf)
                acc[rf][nf] = __builtin_amdgcn_mfma_f32_16x16x32_bf16(wv, f[rf], acc[rf][nf], 0, 0, 0);
        }
    }

    #pragma unroll
    for (int rf = 0; rf < 4; ++rf) {
        const int m = m0 + rf * 16 + l15;
        if (m < N_NODES) {
            #pragma unroll
            for (int nf = 0; nf < 4; ++nf) {
                const int n = w * 64 + nf * 16 + lhi * 4;
                float4 bb = *(const float4*)&b_in[n];
                uint2 pk;
                pk.x = pack2(acc[rf][nf][0] + bb.x, acc[rf][nf][1] + bb.y);
                pk.y = pack2(acc[rf][nf][2] + bb.z, acc[rf][nf][3] + bb.w);
                *(uint2*)&l1[(size_t)m * 256 + n] = pk;
            }
        }
    }
}

// ---------------------------------------------------------------------------
// K2: z = mean_17(l1 rows); h = relu(exp0(z)); l2 = log0(h)   (bf16 -> bf16)
// ---------------------------------------------------------------------------
__global__ __launch_bounds__(256) void k_hat1(
    const ushort* __restrict__ lin, const int* __restrict__ src,
    ushort* __restrict__ lout)
{
    const int lane = threadIdx.x & 63;
    const int half = lane >> 5;
    const int li   = lane & 31;
    const int v    = blockIdx.x * 4 + (threadIdx.x >> 6);
    const int vv   = __builtin_amdgcn_readfirstlane(v);

    const int* sp = src + (size_t)vv * DEG;
    const size_t cb = (size_t)li << 4;

    uint4 r[8];
    #pragma unroll
    for (int j = 0; j < 8; j++) {
        int s0 = sp[j];
        int s1 = sp[j + 8];
        size_t sidx = (size_t)(half ? s1 : s0);
        r[j] = *(const uint4*)((const char*)lin + (sidx << 9) + cb);
    }

    float acc[8];
    #pragma unroll
    for (int i = 0; i < 8; i++) acc[i] = 0.f;
    #pragma unroll
    for (int j = 0; j < 8; j++) {
        acc[0] += bf2f_lo(r[j].x); acc[1] += bf2f_hi(r[j].x);
        acc[2] += bf2f_lo(r[j].y); acc[3] += bf2f_hi(r[j].y);
        acc[4] += bf2f_lo(r[j].z); acc[5] += bf2f_hi(r[j].z);
        acc[6] += bf2f_lo(r[j].w); acc[7] += bf2f_hi(r[j].w);
    }
    if (half == 0) {
        uint4 rs = *(const uint4*)((const char*)lin + ((size_t)vv << 9) + cb);
        acc[0] += bf2f_lo(rs.x); acc[1] += bf2f_hi(rs.x);
        acc[2] += bf2f_lo(rs.y); acc[3] += bf2f_hi(rs.y);
        acc[4] += bf2f_lo(rs.z); acc[5] += bf2f_hi(rs.z);
        acc[6] += bf2f_lo(rs.w); acc[7] += bf2f_hi(rs.w);
    }
    #pragma unroll
    for (int i = 0; i < 8; i++)
        acc[i] = pl32_sum(acc[i]);

    const float inv = 1.f / (float)(DEG + 1);
    float z[8], rz[8], ss = 0.f, ssp = 0.f;
    #pragma unroll
    for (int i = 0; i < 8; i++) {
        z[i] = acc[i] * inv;
        ss += z[i] * z[i];
        rz[i] = fmaxf(z[i], 0.f);
        ssp += rz[i] * rz[i];
    }
    ss  = red32(ss);
    ssp = red32(ssp);

    float norm = sqrtf(ss);
    float nm = fmaxf(norm, EPSF);
    float se = tanh_over_x(nm);               // exp0 scale
    float nh = se * sqrtf(ssp);               // ||relu(exp0(z))||
    float nc = fminf(fmaxf(nh, EPSF), 1.f - EPSF);
    float c  = atanh_over_x(nc) * se;         // combined log0(relu(exp0)) scale

    uint p0 = pack2(c * rz[0], c * rz[1]);
    uint p1 = pack2(c * rz[2], c * rz[3]);
    uint p2 = pack2(c * rz[4], c * rz[5]);
    uint p3 = pack2(c * rz[6], c * rz[7]);
    uint2 u = half ? make_uint2(p2, p3) : make_uint2(p0, p1);
    *(uint2*)((char*)lout + ((size_t)vv << 9) + (li << 4) + (half << 3)) = u;
}

// ---------------------------------------------------------------------------
// K3: z2 = mean_17(l2 rows) -> bf16  (log0(exp0(z2)) identity)
// ---------------------------------------------------------------------------
__global__ __launch_bounds__(256) void k_hat2(
    const ushort* __restrict__ lin, const int* __restrict__ src,
    ushort* __restrict__ z2b)
{
    const int lane = threadIdx.x & 63;
    const int half = lane >> 5;
    const int li   = lane & 31;
    const int v    = blockIdx.x * 4 + (threadIdx.x >> 6);
    const int vv   = __builtin_amdgcn_readfirstlane(v);

    const int* sp = src + (size_t)vv * DEG;
    const size_t cb = (size_t)li << 4;

    uint4 r[8];
    #pragma unroll
    for (int j = 0; j < 8; j++) {
        int s0 = sp[j];
        int s1 = sp[j + 8];
        size_t sidx = (size_t)(half ? s1 : s0);
        r[j] = *(const uint4*)((const char*)lin + (sidx << 9) + cb);
    }

    float acc[8];
    #pragma unroll
    for (int i = 0; i < 8; i++) acc[i] = 0.f;
    #pragma unroll
    for (int j = 0; j < 8; j++) {
        acc[0] += bf2f_lo(r[j].x); acc[1] += bf2f_hi(r[j].x);
        acc[2] += bf2f_lo(r[j].y); acc[3] += bf2f_hi(r[j].y);
        acc[4] += bf2f_lo(r[j].z); acc[5] += bf2f_hi(r[j].z);
        acc[6] += bf2f_lo(r[j].w); acc[7] += bf2f_hi(r[j].w);
    }
    if (half == 0) {
        uint4 rs = *(const uint4*)((const char*)lin + ((size_t)vv << 9) + cb);
        acc[0] += bf2f_lo(rs.x); acc[1] += bf2f_hi(rs.x);
        acc[2] += bf2f_lo(rs.y); acc[3] += bf2f_hi(rs.y);
        acc[4] += bf2f_lo(rs.z); acc[5] += bf2f_hi(rs.z);
        acc[6] += bf2f_lo(rs.w); acc[7] += bf2f_hi(rs.w);
    }
    #pragma unroll
    for (int i = 0; i < 8; i++)
        acc[i] = pl32_sum(acc[i]);

    const float inv = 1.f / (float)(DEG + 1);
    uint2 u;
    if (half == 0)
        u = make_uint2(pack2(acc[0] * inv, acc[1] * inv), pack2(acc[2] * inv, acc[3] * inv));
    else
        u = make_uint2(pack2(acc[4] * inv, acc[5] * inv), pack2(acc[6] * inv, acc[7] * inv));
    *(uint2*)((char*)z2b + ((size_t)vv << 9) + (li << 4) + (half << 3)) = u;
}

// ---------------------------------------------------------------------------
// K4: out = exp0(z2 @ W_out + b_out)  (bf16 MFMA, swapped operands).
// ---------------------------------------------------------------------------
__global__ __launch_bounds__(256) void k_fc_out_mfma(
    const ushort* __restrict__ z2b, const ushort* __restrict__ Wo_t,
    const float* __restrict__ b_out, float* __restrict__ out)
{
    const int t    = threadIdx.x;
    const int lane = t & 63;
    const int w    = t >> 6;
    const int l15  = lane & 15;
    const int lhi  = lane >> 4;
    const int m0   = blockIdx.x * 128;

    f32x4 acc[2][8];
    #pragma unroll
    for (int rf = 0; rf < 2; ++rf)
        #pragma unroll
        for (int nf = 0; nf < 8; ++nf)
            acc[rf][nf] = (f32x4){0.f, 0.f, 0.f, 0.f};

    const ushort* Ap = z2b + (size_t)(m0 + w * 32 + l15) * 256 + lhi * 8;
    const ushort* Wp = Wo_t + (size_t)l15 * 256 + lhi * 8;

    for (int kk = 0; kk < 8; ++kk) {
        bf16x8 f0 = *(const bf16x8*)(Ap + kk * 32);
        bf16x8 f1 = *(const bf16x8*)(Ap + 16 * 256 + kk * 32);
        #pragma unroll
        for (int nf = 0; nf < 8; ++nf) {
            bf16x8 wv = *(const bf16x8*)(Wp + (size_t)nf * 16 * 256 + kk * 32);
            acc[0][nf] = __builtin_amdgcn_mfma_f32_16x16x32_bf16(wv, f0, acc[0][nf], 0, 0, 0);
            acc[1][nf] = __builtin_amdgcn_mfma_f32_16x16x32_bf16(wv, f1, acc[1][nf], 0, 0, 0);
        }
    }

    float4 bb[8];
    #pragma unroll
    for (int nf = 0; nf < 8; ++nf)
        bb[nf] = *(const float4*)&b_out[nf * 16 + lhi * 4];

    #pragma unroll
    for (int rf = 0; rf < 2; ++rf) {
        const int m = m0 + w * 32 + rf * 16 + l15;
        float ss = 0.f;
        #pragma unroll
        for (int nf = 0; nf < 8; ++nf) {
            float t0 = acc[rf][nf][0] + bb[nf].x;
            float t1 = acc[rf][nf][1] + bb[nf].y;
            float t2 = acc[rf][nf][2] + bb[nf].z;
            float t3 = acc[rf][nf][3] + bb[nf].w;
            acc[rf][nf][0] = t0; acc[rf][nf][1] = t1;
            acc[rf][nf][2] = t2; acc[rf][nf][3] = t3;
            ss += t0 * t0 + t1 * t1 + t2 * t2 + t3 * t3;
        }
        ss = pl16_sum(ss);
        ss = pl32_sum(ss);
        float norm = sqrtf(ss);
        float nm = fmaxf(norm, EPSF);
        float se = tanh_over_x(nm);
        if (m < N_NODES) {
            #pragma unroll
            for (int nf = 0; nf < 8; ++nf) {
                float4 o;
                o.x = se * acc[rf][nf][0];
                o.y = se * acc[rf][nf][1];
                o.z = se * acc[rf][nf][2];
                o.w = se * acc[rf][nf][3];
                *(float4*)&out[(size_t)m * 128 + nf * 16 + lhi * 4] = o;
            }
        }
    }
}

extern "C" void kernel_launch(void* const* d_in, const int* in_sizes, int n_in,
                              void* d_out, int out_size, void* d_ws, size_t ws_size,
                              hipStream_t stream) {
    const int*   x     = (const int*)  d_in[0];
    const float* emb0  = (const float*)d_in[1];
    const float* emb1  = (const float*)d_in[2];
    const float* emb2  = (const float*)d_in[3];
    const float* W_in  = (const float*)d_in[4];
    const float* b_in  = (const float*)d_in[5];
    const float* W_out = (const float*)d_in[6];
    const float* b_out = (const float*)d_in[7];
    const int*   src0  = (const int*)  d_in[8];
    const int*   src1  = (const int*)  d_in[10];
    float* out = (float*)d_out;

    ushort* l1  = (ushort*)d_ws;                          // 25.6 MB
    ushort* l2  = l1 + (size_t)N_NODES * 256;             // 25.6 MB
    ushort* z2b = l2 + (size_t)N_NODES * 256;             // 25.6 MB
    ushort* W_t = z2b + (size_t)N_NODES * 256;            // 128 KB
    ushort* Wo_t = W_t + 256 * 256;                       // 64 KB

    k_prep<<<384, 256, 0, stream>>>(W_in, W_out, W_t, Wo_t);
    k_encode_mfma<<<(N_NODES + 63) / 64, 256, 0, stream>>>(x, emb0, emb1, emb2, W_t, b_in, l1);
    k_hat1<<<N_NODES / 4, 256, 0, stream>>>(l1, src0, l2);
    k_hat2<<<N_NODES / 4, 256, 0, stream>>>(l2, src1, z2b);
    k_fc_out_mfma<<<(N_NODES + 127) / 128, 256, 0, stream>>>(z2b, Wo_t, b_out, out);
}